// Round 1
// baseline (44903.391 us; speedup 1.0000x reference)
//
#include <hip/hip_runtime.h>

typedef unsigned int   uint;
typedef unsigned short ushort;

#define NINP    512
#define NHID    1024
#define T_STEPS 512
#define B_SZ    64
#define KTOT    1536                 // NINP + NHID fused K
#define BN      (B_SZ * NHID)        // 65536

typedef __attribute__((ext_vector_type(8))) short bf16x8;
typedef __attribute__((ext_vector_type(4))) float f32x4;

// ---------------- ws layout (bytes) ----------------
#define WCOMB_BYTES (3 * NHID * KTOT * 2)            // 9,437,184
#define WS_BSUM     (WCOMB_BYTES)                    // f32 [3][1024]
#define WS_HHI      (WS_BSUM + 3 * NHID * 4)         // bf16 [64][1024]
#define WS_HLO      (WS_HHI + BN * 2)
#define WS_RHHI     (WS_HLO + BN * 2)
#define WS_RHLO     (WS_RHHI + BN * 2)
#define WS_BAR      (WS_RHLO + BN * 2)               // uint[1024]
#define WS_NEED     (WS_BAR + 4096)

// barrier: 256 blocks = 16 groups x 16; counters on separate 128B lines
#define SUP_IDX 544
#define GEN_IDX 576

__device__ __forceinline__ float sigmoidf_(float x) { return 1.0f / (1.0f + __expf(-x)); }
__device__ __forceinline__ float tanhf_(float x)    { return 1.0f - 2.0f / (__expf(2.0f * x) + 1.0f); }

__device__ __forceinline__ ushort bf16_rne(float f) {
    uint u = __float_as_uint(f);
    return (ushort)((u + 0x7FFFu + ((u >> 16) & 1u)) >> 16);
}
__device__ __forceinline__ float bf16_to_f(ushort s) { return __uint_as_float(((uint)s) << 16); }
__device__ __forceinline__ bf16x8 ld8(const ushort* p) { return *(const bf16x8*)p; }
__device__ __forceinline__ bf16x8 cvt8(const float* p) {
    float4 a = *(const float4*)p;
    float4 b = *(const float4*)(p + 4);
    bf16x8 r;
    r[0] = (short)bf16_rne(a.x); r[1] = (short)bf16_rne(a.y);
    r[2] = (short)bf16_rne(a.z); r[3] = (short)bf16_rne(a.w);
    r[4] = (short)bf16_rne(b.x); r[5] = (short)bf16_rne(b.y);
    r[6] = (short)bf16_rne(b.z); r[7] = (short)bf16_rne(b.w);
    return r;
}
__device__ __forceinline__ f32x4 zero4() { f32x4 z = {0.f, 0.f, 0.f, 0.f}; return z; }
#define MFMA(a, b, c) __builtin_amdgcn_mfma_f32_16x16x32_bf16((a), (b), (c), 0, 0, 0)

// ---------------- prep: weights -> fused bf16 layout ----------------
__global__ __launch_bounds__(256) void prep_w(
    const float* __restrict__ Wiz, const float* __restrict__ Wir, const float* __restrict__ Wih,
    const float* __restrict__ Whz, const float* __restrict__ Whr, const float* __restrict__ Whh,
    ushort* __restrict__ wcomb)
{
    int tid = blockIdx.x * 256 + threadIdx.x;
    int oct = tid % (KTOT / 8);
    int row = tid / (KTOT / 8);                      // gate*1024 + n
    int gate = row >> 10, n = row & 1023;
    int k0 = oct * 8;
    const float* src; int off;
    if (k0 < NINP) { src = gate == 0 ? Wiz : (gate == 1 ? Wir : Wih); off = n * NINP + k0; }
    else           { src = gate == 0 ? Whz : (gate == 1 ? Whr : Whh); off = n * NHID + (k0 - NINP); }
    ushort* dst = wcomb + (size_t)row * KTOT + k0;
    #pragma unroll
    for (int j = 0; j < 8; ++j) dst[j] = bf16_rne(src[off + j]);
}

// ---------------- prep: h0 hi/lo, bias sums, barrier zero ----------------
__global__ __launch_bounds__(256) void prep_misc(
    const float* __restrict__ h0,
    const float* __restrict__ biz, const float* __restrict__ bir, const float* __restrict__ bih,
    const float* __restrict__ bhz, const float* __restrict__ bhr, const float* __restrict__ bhh,
    ushort* __restrict__ hhi, ushort* __restrict__ hlo, float* __restrict__ bsum,
    uint* __restrict__ bar)
{
    if (blockIdx.x < 256) {
        int i = blockIdx.x * 256 + threadIdx.x;
        float v = h0[i];
        ushort hi = bf16_rne(v);
        ushort lo = bf16_rne(v - bf16_to_f(hi));
        hhi[i] = hi; hlo[i] = lo;
    } else {
        for (int n = threadIdx.x; n < NHID; n += 256) {
            bsum[n]            = biz[n] + bhz[n];
            bsum[NHID + n]     = bir[n] + bhr[n];
            bsum[2 * NHID + n] = bih[n] + bhh[n];
        }
        for (int i = threadIdx.x; i < 1024; i += 256) bar[i] = 0u;
    }
}

// ---------------- split grid barrier: arrive / wait ----------------
// 256 blocks: 16 groups x 16, two-level relaxed arrivals, release/acquire fences
// at the edges. Split form lets independent work run inside the wait window.
__device__ __forceinline__ void grid_arrive(uint* bar, uint& bgen) {
    __builtin_amdgcn_fence(__ATOMIC_RELEASE, "agent");   // push stores to coherence point
    __syncthreads();
    if (threadIdx.x == 0) {
        bgen = __hip_atomic_load(&bar[GEN_IDX], __ATOMIC_RELAXED, __HIP_MEMORY_SCOPE_AGENT);
        uint grp = blockIdx.x >> 4;
        uint a = __hip_atomic_fetch_add(&bar[grp * 32], 1u, __ATOMIC_RELAXED, __HIP_MEMORY_SCOPE_AGENT);
        if (a == 15u) {
            uint s = __hip_atomic_fetch_add(&bar[SUP_IDX], 1u, __ATOMIC_RELAXED, __HIP_MEMORY_SCOPE_AGENT);
            if (s == 15u) {
                #pragma unroll
                for (int i = 0; i < 16; ++i)
                    __hip_atomic_store(&bar[i * 32], 0u, __ATOMIC_RELAXED, __HIP_MEMORY_SCOPE_AGENT);
                __hip_atomic_store(&bar[SUP_IDX], 0u, __ATOMIC_RELAXED, __HIP_MEMORY_SCOPE_AGENT);
                __hip_atomic_store(&bar[GEN_IDX], bgen + 1u, __ATOMIC_RELEASE, __HIP_MEMORY_SCOPE_AGENT);
            }
        }
    }
}
__device__ __forceinline__ void grid_wait(uint* bar, uint bgen) {
    if (threadIdx.x == 0) {
        while (__hip_atomic_load(&bar[GEN_IDX], __ATOMIC_RELAXED, __HIP_MEMORY_SCOPE_AGENT) == bgen)
            __builtin_amdgcn_s_sleep(1);
    }
    __syncthreads();
    __builtin_amdgcn_fence(__ATOMIC_ACQUIRE, "agent");   // invalidate stale cache lines
}

// ---------------- persistent GRU: 256 blocks x 512 threads ----------------
// Block = (nt, mt): n-cols [nt*16, nt*16+16), batch rows [mt*16, mt*16+16).
// 8 waves split fused K=1536 8-ways: wave wv does K-steps j = wv + 8s, s=0..5
// (s<2: x region, s>=2: h hi+lo region). Cross-wave reduce via LDS; all waves
// redundantly reduce + hold h(t-1) in 4 registers (no shared h buffer, no race).
// Stores split across waves. Next-step x load/cvt/MFMA hidden under barrier-B
// wait; phase-2 x MFMAs hidden under barrier-A wait.
// mt = bid & 3, XCD = bid & 7 -> all blocks on an XCD share the same m-slice
// of x/rh (per-phase L2 reuse).
__global__ __launch_bounds__(512, 2) void gru_persist(
    const float* __restrict__ x, const float* __restrict__ h0,
    const void* __restrict__ lengths_raw,
    const ushort* __restrict__ wcomb, const float* __restrict__ bsum,
    ushort* __restrict__ hhi, ushort* __restrict__ hlo,
    ushort* __restrict__ rhhi, ushort* __restrict__ rhlo,
    uint* __restrict__ bar, float* __restrict__ out)
{
    const int bid = blockIdx.x;
    const int nt = bid >> 2, mt = bid & 3;
    const int nbase = nt * 16, mbase = mt * 16;
    const int tid = threadIdx.x;
    const int wv = tid >> 6, lane = tid & 63;
    const int col = lane & 15, quad = lane >> 4;
    const int q8 = quad * 8;

    __shared__ f32x4 lds_acc[8][2][64];              // [wave][gate][lane]  16 KB

    // ---- weight fragments -> VGPRs (once): 6 K-steps x 3 gates = 72 VGPRs ----
    bf16x8 wfz[6], wfr[6], wfc[6];
    #pragma unroll
    for (int s = 0; s < 6; ++s) {
        const int j = wv + 8 * s;                    // K-step 0..47
        const size_t ko = (size_t)j * 32 + q8;
        wfz[s] = ld8(wcomb + (size_t)(0 * NHID + nbase + col) * KTOT + ko);
        wfr[s] = ld8(wcomb + (size_t)(1 * NHID + nbase + col) * KTOT + ko);
        wfc[s] = ld8(wcomb + (size_t)(2 * NHID + nbase + col) * KTOT + ko);
    }

    // lengths: int64 per reference, int32 if x64 disabled
    const int* l32 = (const int*)lengths_raw;
    const bool is64 = (l32[1] == 0);
    int len[4];
    float h_reg[4];                                  // h(t-1) for rows quad*4+i, col
    #pragma unroll
    for (int i = 0; i < 4; ++i) {
        const int b = mbase + quad * 4 + i;
        len[i]   = is64 ? (int)((const long long*)lengths_raw)[b] : l32[b];
        h_reg[i] = h0[(size_t)b * NHID + nbase + col];
    }

    const float bias_z = bsum[nbase + col];
    const float bias_r = bsum[NHID + nbase + col];
    const float bias_c = bsum[2 * NHID + nbase + col];

    const size_t arow = (size_t)(mbase + col);       // A-operand row (batch index)

    f32x4 zsig = zero4();
    bf16x8 xf[2];                                    // cached x frags for phase 2
    uint bgen = 0;

    // prologue: t=0 x-region into az/ar
    f32x4 az = zero4(), ar = zero4();
    #pragma unroll
    for (int s = 0; s < 2; ++s) {
        const int k = (wv + 8 * s) * 32;
        xf[s] = cvt8(x + arow * NINP + k + q8);
        az = MFMA(xf[s], wfz[s], az);
        ar = MFMA(xf[s], wfr[s], ar);
    }

    for (int t = 0; t < T_STEPS; ++t) {
        // ================= phase 1: z, r (h region) =================
        #pragma unroll
        for (int s = 2; s < 6; ++s) {
            const int kh = (wv + 8 * s) * 32 - NINP;
            const size_t ao = arow * NHID + kh + q8;
            const bf16x8 hi = ld8(hhi + ao);
            const bf16x8 lo = ld8(hlo + ao);
            az = MFMA(hi, wfz[s], az);
            ar = MFMA(hi, wfr[s], ar);
            az = MFMA(lo, wfz[s], az);
            ar = MFMA(lo, wfr[s], ar);
        }
        lds_acc[wv][0][lane] = az;
        lds_acc[wv][1][lane] = ar;
        __syncthreads();
        // all waves redundantly reduce (broadcast reads, keeps zsig everywhere)
        f32x4 zp = {bias_z, bias_z, bias_z, bias_z};
        f32x4 rp = {bias_r, bias_r, bias_r, bias_r};
        #pragma unroll
        for (int w = 0; w < 8; ++w) {
            const f32x4 a = lds_acc[w][0][lane];
            const f32x4 b = lds_acc[w][1][lane];
            #pragma unroll
            for (int i = 0; i < 4; ++i) { zp[i] += a[i]; rp[i] += b[i]; }
        }
        #pragma unroll
        for (int i = 0; i < 4; ++i) {
            zsig[i] = sigmoidf_(zp[i]);
            const float r  = sigmoidf_(rp[i]);
            const float rh = r * h_reg[i];
            const ushort hi16 = bf16_rne(rh);
            const ushort lo16 = bf16_rne(rh - bf16_to_f(hi16));
            const size_t gi = (size_t)(mbase + quad * 4 + i) * NHID + nbase + col;
            if (wv == 0) rhhi[gi] = hi16;
            if (wv == 1) rhlo[gi] = lo16;
        }
        grid_arrive(bar, bgen);                      // A arrive: rh visible device-wide
        f32x4 ac = zero4();                          // independent c x-part in wait window
        ac = MFMA(xf[0], wfc[0], ac);
        ac = MFMA(xf[1], wfc[1], ac);
        grid_wait(bar, bgen);                        // A wait

        // ================= phase 2: c, h update =================
        #pragma unroll
        for (int s = 2; s < 6; ++s) {
            const int kh = (wv + 8 * s) * 32 - NINP;
            const size_t ao = arow * NHID + kh + q8;
            const bf16x8 hi = ld8(rhhi + ao);
            const bf16x8 lo = ld8(rhlo + ao);
            ac = MFMA(hi, wfc[s], ac);
            ac = MFMA(lo, wfc[s], ac);
        }
        lds_acc[wv][0][lane] = ac;                   // prior reads fenced by arrive-A
        __syncthreads();
        f32x4 cp = {bias_c, bias_c, bias_c, bias_c};
        #pragma unroll
        for (int w = 0; w < 8; ++w) {
            const f32x4 a = lds_acc[w][0][lane];
            #pragma unroll
            for (int i = 0; i < 4; ++i) cp[i] += a[i];
        }
        float* out_t = out + (size_t)t * BN;
        #pragma unroll
        for (int i = 0; i < 4; ++i) {
            const float c = tanhf_(cp[i]);
            const float h = h_reg[i];
            const float hn = (t < len[i]) ? fmaf(zsig[i], c - h, h) : h;
            h_reg[i] = hn;
            const size_t gi = (size_t)(mbase + quad * 4 + i) * NHID + nbase + col;
            const ushort hi16 = bf16_rne(hn);
            const ushort lo16 = bf16_rne(hn - bf16_to_f(hi16));
            if (wv == 0) __builtin_nontemporal_store(hn, &out_t[gi]);
            if (wv == 1) hhi[gi] = hi16;
            if (wv == 2) hlo[gi] = lo16;
            if (wv == 3 && t == T_STEPS - 1)
                __builtin_nontemporal_store(hn, &out[(size_t)T_STEPS * BN + gi]);
        }
        grid_arrive(bar, bgen);                      // B arrive: h visible device-wide
        az = zero4(); ar = zero4();                  // next-step x-region in wait window
        if (t + 1 < T_STEPS) {
            const float* x_t = x + (size_t)(t + 1) * B_SZ * NINP;
            #pragma unroll
            for (int s = 0; s < 2; ++s) {
                const int k = (wv + 8 * s) * 32;
                xf[s] = cvt8(x_t + arow * NINP + k + q8);
                az = MFMA(xf[s], wfz[s], az);
                ar = MFMA(xf[s], wfr[s], ar);
            }
        }
        grid_wait(bar, bgen);                        // B wait
    }
}

// ws_size probe: no-op; gridDim.x = ws_size_in_MB + 1 (read from rocprof dims).
__global__ void gru_ws_probe_mb(float* p) {
    if (blockIdx.x == 0xFFFFFFFFu) p[0] = 0.f;
}

extern "C" void kernel_launch(void* const* d_in, const int* in_sizes, int n_in,
                              void* d_out, int out_size, void* d_ws, size_t ws_size,
                              hipStream_t stream) {
    const float* x   = (const float*)d_in[0];
    const float* h0  = (const float*)d_in[1];
    const float* Wiz = (const float*)d_in[2];  const float* biz = (const float*)d_in[3];
    const float* Wir = (const float*)d_in[4];  const float* bir = (const float*)d_in[5];
    const float* Wih = (const float*)d_in[6];  const float* bih = (const float*)d_in[7];
    const float* Whz = (const float*)d_in[8];  const float* bhz = (const float*)d_in[9];
    const float* Whr = (const float*)d_in[10]; const float* bhr = (const float*)d_in[11];
    const float* Whh = (const float*)d_in[12]; const float* bhh = (const float*)d_in[13];
    const void*  lengths = d_in[14];
    float* out = (float*)d_out;
    char*  ws  = (char*)d_ws;

    size_t mb = ws_size >> 20; if (mb > 2048) mb = 2048;
    gru_ws_probe_mb<<<dim3((uint)mb + 1), 64, 0, stream>>>((float*)d_ws);
    if (ws_size < (size_t)WS_NEED) return;

    ushort* wcomb = (ushort*)ws;
    float*  bsum  = (float*)(ws + WS_BSUM);
    ushort* hhi   = (ushort*)(ws + WS_HHI);
    ushort* hlo   = (ushort*)(ws + WS_HLO);
    ushort* rhhi  = (ushort*)(ws + WS_RHHI);
    ushort* rhlo  = (ushort*)(ws + WS_RHLO);
    uint*   bar   = (uint*)(ws + WS_BAR);

    prep_w<<<2304, 256, 0, stream>>>(Wiz, Wir, Wih, Whz, Whr, Whh, wcomb);
    prep_misc<<<257, 256, 0, stream>>>(h0, biz, bir, bih, bhz, bhr, bhh, hhi, hlo, bsum, bar);
    gru_persist<<<256, 512, 0, stream>>>(x, h0, lengths, wcomb, bsum,
                                         hhi, hlo, rhhi, rhlo, bar, out);
}

// Round 2
// 5357.375 us; speedup vs baseline: 8.3816x; 8.3816x over previous
//
#include <hip/hip_runtime.h>

typedef unsigned int   uint;
typedef unsigned short ushort;

#define NINP    512
#define NHID    1024
#define T_STEPS 512
#define B_SZ    64
#define KTOT    1536                 // NINP + NHID fused K
#define BN      (B_SZ * NHID)        // 65536

typedef __attribute__((ext_vector_type(8))) short bf16x8;
typedef __attribute__((ext_vector_type(4))) float f32x4;
typedef __attribute__((ext_vector_type(4))) uint  uintx4;

// ---------------- ws layout (bytes) ----------------
#define WCOMB_BYTES (3 * NHID * KTOT * 2)            // 9,437,184
#define WS_BSUM     (WCOMB_BYTES)                    // f32 [3][1024]
#define WS_HP       (WS_BSUM + 3 * NHID * 4)         // uint [64][1024] packed h  (hi|lo<<16)
#define WS_RHP      (WS_HP + BN * 4)                 // uint [64][1024] packed r*h
#define WS_BAR      (WS_RHP + BN * 4)                // uint[2048]
#define WS_NEED     (WS_BAR + 8192)                  // ~9.52 MB (same as R0 budget)

// barrier: 256 blocks = 16 groups x 16; each counter/wake on its own 128B line
#define NGRP     16
#define SUP_IDX  544
#define WAKE_IDX(g) (640 + (g) * 32)

__device__ __forceinline__ float sigmoidf_(float x) { return 1.0f / (1.0f + __expf(-x)); }
__device__ __forceinline__ float tanhf_(float x)    { return 1.0f - 2.0f / (__expf(2.0f * x) + 1.0f); }

__device__ __forceinline__ ushort bf16_rne(float f) {
    uint u = __float_as_uint(f);
    return (ushort)((u + 0x7FFFu + ((u >> 16) & 1u)) >> 16);
}
__device__ __forceinline__ float bf16_to_f(ushort s) { return __uint_as_float(((uint)s) << 16); }
__device__ __forceinline__ bf16x8 ld8(const ushort* p) { return *(const bf16x8*)p; }
__device__ __forceinline__ bf16x8 cvt8(const float* p) {
    float4 a = *(const float4*)p;
    float4 b = *(const float4*)(p + 4);
    bf16x8 r;
    r[0] = (short)bf16_rne(a.x); r[1] = (short)bf16_rne(a.y);
    r[2] = (short)bf16_rne(a.z); r[3] = (short)bf16_rne(a.w);
    r[4] = (short)bf16_rne(b.x); r[5] = (short)bf16_rne(b.y);
    r[6] = (short)bf16_rne(b.z); r[7] = (short)bf16_rne(b.w);
    return r;
}
__device__ __forceinline__ f32x4 zero4() { f32x4 z = {0.f, 0.f, 0.f, 0.f}; return z; }
#define MFMA(a, b, c) __builtin_amdgcn_mfma_f32_16x16x32_bf16((a), (b), (c), 0, 0, 0)

// ---------------- MALL-coherent primitives (no cache-maintenance fences) ----
__device__ __forceinline__ uint ld_rlx(uint* p) {
    return __hip_atomic_load(p, __ATOMIC_RELAXED, __HIP_MEMORY_SCOPE_AGENT);
}
__device__ __forceinline__ void st_rlx(uint* p, uint v) {
    __hip_atomic_store(p, v, __ATOMIC_RELAXED, __HIP_MEMORY_SCOPE_AGENT);
}
__device__ __forceinline__ uint add_rlx(uint* p, uint v) {
    return __hip_atomic_fetch_add(p, v, __ATOMIC_RELAXED, __HIP_MEMORY_SCOPE_AGENT);
}
// 32B state read straight from MALL (bypass L1+L2): two dwordx4 with sc0 sc1.
__device__ __forceinline__ void ld_state(const uint* p, uintx4& a, uintx4& b) {
    asm volatile("global_load_dwordx4 %0, %1, off sc0 sc1"
                 : "=v"(a) : "v"(p) : "memory");
    asm volatile("global_load_dwordx4 %0, %1, off offset:16 sc0 sc1"
                 : "=v"(b) : "v"(p) : "memory");
}
// packed uint = hi16 | lo16<<16 ; split 8 packed words into hi/lo bf16x8 frags
__device__ __forceinline__ bf16x8 hi_frag(uintx4 a, uintx4 b) {
    uintx4 r;
    r[0] = __builtin_amdgcn_perm(a[1], a[0], 0x05040100u);
    r[1] = __builtin_amdgcn_perm(a[3], a[2], 0x05040100u);
    r[2] = __builtin_amdgcn_perm(b[1], b[0], 0x05040100u);
    r[3] = __builtin_amdgcn_perm(b[3], b[2], 0x05040100u);
    return *(bf16x8*)&r;
}
__device__ __forceinline__ bf16x8 lo_frag(uintx4 a, uintx4 b) {
    uintx4 r;
    r[0] = __builtin_amdgcn_perm(a[1], a[0], 0x07060302u);
    r[1] = __builtin_amdgcn_perm(a[3], a[2], 0x07060302u);
    r[2] = __builtin_amdgcn_perm(b[1], b[0], 0x07060302u);
    r[3] = __builtin_amdgcn_perm(b[3], b[2], 0x07060302u);
    return *(bf16x8*)&r;
}
__device__ __forceinline__ uint pack_hl(float v) {
    ushort hi = bf16_rne(v);
    ushort lo = bf16_rne(v - bf16_to_f(hi));
    return (uint)hi | ((uint)lo << 16);
}

// ---------------- prep: weights -> fused bf16 layout ----------------
__global__ __launch_bounds__(256) void prep_w(
    const float* __restrict__ Wiz, const float* __restrict__ Wir, const float* __restrict__ Wih,
    const float* __restrict__ Whz, const float* __restrict__ Whr, const float* __restrict__ Whh,
    ushort* __restrict__ wcomb)
{
    int tid = blockIdx.x * 256 + threadIdx.x;
    int oct = tid % (KTOT / 8);
    int row = tid / (KTOT / 8);                      // gate*1024 + n
    int gate = row >> 10, n = row & 1023;
    int k0 = oct * 8;
    const float* src; int off;
    if (k0 < NINP) { src = gate == 0 ? Wiz : (gate == 1 ? Wir : Wih); off = n * NINP + k0; }
    else           { src = gate == 0 ? Whz : (gate == 1 ? Whr : Whh); off = n * NHID + (k0 - NINP); }
    ushort* dst = wcomb + (size_t)row * KTOT + k0;
    #pragma unroll
    for (int j = 0; j < 8; ++j) dst[j] = bf16_rne(src[off + j]);
}

// ---------------- prep: packed h0, bias sums, barrier zero ----------------
__global__ __launch_bounds__(256) void prep_misc(
    const float* __restrict__ h0,
    const float* __restrict__ biz, const float* __restrict__ bir, const float* __restrict__ bih,
    const float* __restrict__ bhz, const float* __restrict__ bhr, const float* __restrict__ bhh,
    uint* __restrict__ hp, float* __restrict__ bsum, uint* __restrict__ bar)
{
    if (blockIdx.x < 256) {
        int i = blockIdx.x * 256 + threadIdx.x;
        hp[i] = pack_hl(h0[i]);
    } else {
        for (int n = threadIdx.x; n < NHID; n += 256) {
            bsum[n]            = biz[n] + bhz[n];
            bsum[NHID + n]     = bir[n] + bhr[n];
            bsum[2 * NHID + n] = bih[n] + bhh[n];
        }
        for (int i = threadIdx.x; i < 2048; i += 256) bar[i] = 0u;
    }
}

// ---------------- fence-free grid barrier: relaxed atomics only ------------
// arrive: pre-s_barrier waitcnt (compiler) drains this block's sc0sc1 stores
// to the MALL; then one relaxed fetch_add per block, two-level tree. The last
// block resets counters, waits vmcnt(0) (resets at MALL), then publishes the
// generation on 16 per-group wake lines. wait: poll own group's line.
__device__ __forceinline__ void grid_arrive(uint* bar, int grp, uint bgen) {
    __syncthreads();
    if (threadIdx.x == 0) {
        uint a = add_rlx(&bar[grp * 32], 1u);
        if (a == 15u) {
            uint s = add_rlx(&bar[SUP_IDX], 1u);
            if (s == 15u) {
                #pragma unroll
                for (int g = 0; g < NGRP; ++g) st_rlx(&bar[g * 32], 0u);
                st_rlx(&bar[SUP_IDX], 0u);
                asm volatile("s_waitcnt vmcnt(0)" ::: "memory");
                #pragma unroll
                for (int g = 0; g < NGRP; ++g) st_rlx(&bar[WAKE_IDX(g)], bgen + 1u);
            }
        }
    }
}
__device__ __forceinline__ void grid_wait(uint* bar, int grp, uint& bgen) {
    if (threadIdx.x == 0) {
        while (ld_rlx(&bar[WAKE_IDX(grp)]) != bgen + 1u)
            __builtin_amdgcn_s_sleep(1);
    }
    bgen++;
    __syncthreads();
}

// ---------------- persistent GRU: 256 blocks x 512 threads ----------------
// Block = (nt, mt): n-cols [nt*16,+16), batch rows [mt*16,+16). 8 waves split
// fused K=1536: wave wv does K-steps j = wv + 8s (s=0..5; s<2 x, s>=2 h).
// Recurrent state (h, r*h) exchanged as packed hi|lo bf16 uints through the
// MALL via relaxed atomics / sc0sc1 loads — no L2 writeback/invalidate ever.
// 86KB LDS pins 1 block/CU (deterministic placement). Next-step x MFMAs run
// in barrier-B wait window; candidate x MFMAs in barrier-A window.
__global__ __launch_bounds__(512, 1) void gru_persist(
    const float* __restrict__ x, const float* __restrict__ h0,
    const void* __restrict__ lengths_raw,
    const ushort* __restrict__ wcomb, const float* __restrict__ bsum,
    uint* __restrict__ hp, uint* __restrict__ rhp,
    uint* __restrict__ bar, float* __restrict__ out)
{
    const int bid = blockIdx.x;
    const int nt = bid >> 2, mt = bid & 3;
    const int nbase = nt * 16, mbase = mt * 16;
    const int grp = bid >> 4;                        // 16 groups x 16 blocks
    const int tid = threadIdx.x;
    const int wv = tid >> 6, lane = tid & 63;
    const int col = lane & 15, quad = lane >> 4;
    const int q8 = quad * 8;

    __shared__ f32x4 lds_acc[8][2][64];              // 16 KB
    __shared__ uint  lds_pad[17408];                 // 68 KB -> 1 block/CU

    // ---- weight fragments -> VGPRs (once): 6 K-steps x 3 gates ----
    bf16x8 wfz[6], wfr[6], wfc[6];
    #pragma unroll
    for (int s = 0; s < 6; ++s) {
        const int j = wv + 8 * s;                    // K-step 0..47
        const size_t ko = (size_t)j * 32 + q8;
        wfz[s] = ld8(wcomb + (size_t)(0 * NHID + nbase + col) * KTOT + ko);
        wfr[s] = ld8(wcomb + (size_t)(1 * NHID + nbase + col) * KTOT + ko);
        wfc[s] = ld8(wcomb + (size_t)(2 * NHID + nbase + col) * KTOT + ko);
    }

    const int* l32 = (const int*)lengths_raw;
    const bool is64 = (l32[1] == 0);
    int len[4];
    float h_reg[4];                                  // h(t-1) rows quad*4+i, col
    #pragma unroll
    for (int i = 0; i < 4; ++i) {
        const int b = mbase + quad * 4 + i;
        len[i]   = is64 ? (int)((const long long*)lengths_raw)[b] : l32[b];
        h_reg[i] = h0[(size_t)b * NHID + nbase + col];
    }

    const float bias_z = bsum[nbase + col];
    const float bias_r = bsum[NHID + nbase + col];
    const float bias_c = bsum[2 * NHID + nbase + col];

    const size_t arow = (size_t)(mbase + col);       // A-operand row (batch)

    f32x4 zsig = zero4();
    bf16x8 xf[2];
    uint bgen = 0;

    // prologue: t=0 x-region
    f32x4 az = zero4(), ar = zero4();
    #pragma unroll
    for (int s = 0; s < 2; ++s) {
        const int k = (wv + 8 * s) * 32;
        xf[s] = cvt8(x + arow * NINP + k + q8);
        az = MFMA(xf[s], wfz[s], az);
        ar = MFMA(xf[s], wfr[s], ar);
    }

    for (int t = 0; t < T_STEPS; ++t) {
        // ================= phase 1: z, r (h region) =================
        {
            uintx4 qa[4], qb[4];
            #pragma unroll
            for (int s = 0; s < 4; ++s) {
                const int kh = (wv + 8 * (s + 2)) * 32 - NINP;
                ld_state(hp + arow * NHID + kh + q8, qa[s], qb[s]);
            }
            asm volatile("s_waitcnt vmcnt(0)" ::: "memory");
            __builtin_amdgcn_sched_barrier(0);
            #pragma unroll
            for (int s = 0; s < 4; ++s) {
                const bf16x8 hi = hi_frag(qa[s], qb[s]);
                const bf16x8 lo = lo_frag(qa[s], qb[s]);
                az = MFMA(hi, wfz[s + 2], az);
                ar = MFMA(hi, wfr[s + 2], ar);
                az = MFMA(lo, wfz[s + 2], az);
                ar = MFMA(lo, wfr[s + 2], ar);
            }
        }
        lds_acc[wv][0][lane] = az;
        lds_acc[wv][1][lane] = ar;
        __syncthreads();
        f32x4 zp = {bias_z, bias_z, bias_z, bias_z};
        f32x4 rp = {bias_r, bias_r, bias_r, bias_r};
        #pragma unroll
        for (int w = 0; w < 8; ++w) {
            const f32x4 a = lds_acc[w][0][lane];
            const f32x4 b = lds_acc[w][1][lane];
            #pragma unroll
            for (int i = 0; i < 4; ++i) { zp[i] += a[i]; rp[i] += b[i]; }
        }
        #pragma unroll
        for (int i = 0; i < 4; ++i) {
            zsig[i] = sigmoidf_(zp[i]);
            if (wv == 0) {
                const float r  = sigmoidf_(rp[i]);
                const float rh = r * h_reg[i];
                const size_t gi = (size_t)(mbase + quad * 4 + i) * NHID + nbase + col;
                st_rlx(&rhp[gi], pack_hl(rh));
            }
        }
        grid_arrive(bar, grp, bgen);                 // A: rh at MALL device-wide
        f32x4 ac = zero4();                          // candidate x-part in window
        ac = MFMA(xf[0], wfc[0], ac);
        ac = MFMA(xf[1], wfc[1], ac);
        grid_wait(bar, grp, bgen);                   // A wait

        // ================= phase 2: c, h update =================
        {
            uintx4 qa[4], qb[4];
            #pragma unroll
            for (int s = 0; s < 4; ++s) {
                const int kh = (wv + 8 * (s + 2)) * 32 - NINP;
                ld_state(rhp + arow * NHID + kh + q8, qa[s], qb[s]);
            }
            asm volatile("s_waitcnt vmcnt(0)" ::: "memory");
            __builtin_amdgcn_sched_barrier(0);
            #pragma unroll
            for (int s = 0; s < 4; ++s) {
                const bf16x8 hi = hi_frag(qa[s], qb[s]);
                const bf16x8 lo = lo_frag(qa[s], qb[s]);
                ac = MFMA(hi, wfc[s + 2], ac);
                ac = MFMA(lo, wfc[s + 2], ac);
            }
        }
        lds_acc[wv][0][lane] = ac;
        __syncthreads();
        f32x4 cp = {bias_c, bias_c, bias_c, bias_c};
        #pragma unroll
        for (int w = 0; w < 8; ++w) {
            const f32x4 a = lds_acc[w][0][lane];
            #pragma unroll
            for (int i = 0; i < 4; ++i) cp[i] += a[i];
        }
        float* out_t = out + (size_t)t * BN;
        #pragma unroll
        for (int i = 0; i < 4; ++i) {
            const float c = tanhf_(cp[i]);
            const float h = h_reg[i];
            const float hn = (t < len[i]) ? fmaf(zsig[i], c - h, h) : h;
            h_reg[i] = hn;
            const size_t gi = (size_t)(mbase + quad * 4 + i) * NHID + nbase + col;
            if (wv == 0) __builtin_nontemporal_store(hn, &out_t[gi]);
            if (wv == 1) st_rlx(&hp[gi], pack_hl(hn));
            if (wv == 3 && t == T_STEPS - 1)
                __builtin_nontemporal_store(hn, &out[(size_t)T_STEPS * BN + gi]);
        }
        grid_arrive(bar, grp, bgen);                 // B: h at MALL device-wide
        az = zero4(); ar = zero4();                  // next-step x in window
        if (t + 1 < T_STEPS) {
            const float* x_t = x + (size_t)(t + 1) * B_SZ * NINP;
            #pragma unroll
            for (int s = 0; s < 2; ++s) {
                const int k = (wv + 8 * s) * 32;
                xf[s] = cvt8(x_t + arow * NINP + k + q8);
                az = MFMA(xf[s], wfz[s], az);
                ar = MFMA(xf[s], wfr[s], ar);
            }
        }
        grid_wait(bar, grp, bgen);                   // B wait
    }

    // keep lds_pad allocated (unprovable guard; never executes)
    if (blockIdx.x == 0xFFFFFFFFu) {
        lds_pad[threadIdx.x] = bgen;
        out[0] = (float)lds_pad[threadIdx.x];
    }
}

// ws_size probe: no-op; gridDim.x = ws_size_in_MB + 1 (read from rocprof dims).
__global__ void gru_ws_probe_mb(float* p) {
    if (blockIdx.x == 0xFFFFFFFFu) p[0] = 0.f;
}

extern "C" void kernel_launch(void* const* d_in, const int* in_sizes, int n_in,
                              void* d_out, int out_size, void* d_ws, size_t ws_size,
                              hipStream_t stream) {
    const float* x   = (const float*)d_in[0];
    const float* h0  = (const float*)d_in[1];
    const float* Wiz = (const float*)d_in[2];  const float* biz = (const float*)d_in[3];
    const float* Wir = (const float*)d_in[4];  const float* bir = (const float*)d_in[5];
    const float* Wih = (const float*)d_in[6];  const float* bih = (const float*)d_in[7];
    const float* Whz = (const float*)d_in[8];  const float* bhz = (const float*)d_in[9];
    const float* Whr = (const float*)d_in[10]; const float* bhr = (const float*)d_in[11];
    const float* Whh = (const float*)d_in[12]; const float* bhh = (const float*)d_in[13];
    const void*  lengths = d_in[14];
    float* out = (float*)d_out;
    char*  ws  = (char*)d_ws;

    size_t mb = ws_size >> 20; if (mb > 2048) mb = 2048;
    gru_ws_probe_mb<<<dim3((uint)mb + 1), 64, 0, stream>>>((float*)d_ws);
    if (ws_size < (size_t)WS_NEED) return;

    ushort* wcomb = (ushort*)ws;
    float*  bsum  = (float*)(ws + WS_BSUM);
    uint*   hp    = (uint*)(ws + WS_HP);
    uint*   rhp   = (uint*)(ws + WS_RHP);
    uint*   bar   = (uint*)(ws + WS_BAR);

    prep_w<<<2304, 256, 0, stream>>>(Wiz, Wir, Wih, Whz, Whr, Whh, wcomb);
    prep_misc<<<257, 256, 0, stream>>>(h0, biz, bir, bih, bhz, bhr, bhh, hp, bsum, bar);
    gru_persist<<<256, 512, 0, stream>>>(x, h0, lengths, wcomb, bsum,
                                         hp, rhp, bar, out);
}

// Round 3
// 4761.616 us; speedup vs baseline: 9.4303x; 1.1251x over previous
//
#include <hip/hip_runtime.h>

typedef unsigned int   uint;
typedef unsigned short ushort;

#define NINP    512
#define NHID    1024
#define T_STEPS 512
#define B_SZ    64
#define KTOT    1536                 // NINP + NHID fused K
#define BN      (B_SZ * NHID)        // 65536

typedef __attribute__((ext_vector_type(8))) short bf16x8;
typedef __attribute__((ext_vector_type(4))) float f32x4;
typedef __attribute__((ext_vector_type(4))) uint  uintx4;

// ---------------- ws layout (bytes) ----------------
#define WCOMB_BYTES (3 * NHID * KTOT * 2)            // 9,437,184
#define WS_BSUM     (WCOMB_BYTES)                    // f32 [3][1024]
#define WS_HP       (WS_BSUM + 3 * NHID * 4)         // uint [64][1024] packed h  (hi|lo<<16)
#define WS_RHP      (WS_HP + BN * 4)                 // uint [64][1024] packed r*h
#define WS_BAR      (WS_RHP + BN * 4)                // uint[4096]: 4 gangs x 1024
#define WS_NEED     (WS_BAR + 16384)

// gang barrier (uint indices inside a gang's 1024-uint region):
// 8 group counters at oct*32 (monotonic, never reset), sup at 256,
// 8 wake lines at 384 + oct*32. All on distinct 128B lines.
#define G_SUP   256
#define G_WAKE  384

__device__ __forceinline__ float sigmoidf_(float x) { return 1.0f / (1.0f + __expf(-x)); }
__device__ __forceinline__ float tanhf_(float x)    { return 1.0f - 2.0f / (__expf(2.0f * x) + 1.0f); }

__device__ __forceinline__ ushort bf16_rne(float f) {
    uint u = __float_as_uint(f);
    return (ushort)((u + 0x7FFFu + ((u >> 16) & 1u)) >> 16);
}
__device__ __forceinline__ float bf16_to_f(ushort s) { return __uint_as_float(((uint)s) << 16); }
__device__ __forceinline__ bf16x8 ld8(const ushort* p) { return *(const bf16x8*)p; }
__device__ __forceinline__ bf16x8 cvt8(const float* p) {
    float4 a = *(const float4*)p;
    float4 b = *(const float4*)(p + 4);
    bf16x8 r;
    r[0] = (short)bf16_rne(a.x); r[1] = (short)bf16_rne(a.y);
    r[2] = (short)bf16_rne(a.z); r[3] = (short)bf16_rne(a.w);
    r[4] = (short)bf16_rne(b.x); r[5] = (short)bf16_rne(b.y);
    r[6] = (short)bf16_rne(b.z); r[7] = (short)bf16_rne(b.w);
    return r;
}
__device__ __forceinline__ f32x4 zero4() { f32x4 z = {0.f, 0.f, 0.f, 0.f}; return z; }
#define MFMA(a, b, c) __builtin_amdgcn_mfma_f32_16x16x32_bf16((a), (b), (c), 0, 0, 0)

// ---------------- MALL-coherent primitives (no cache-maintenance fences) ----
__device__ __forceinline__ uint ld_rlx(uint* p) {
    return __hip_atomic_load(p, __ATOMIC_RELAXED, __HIP_MEMORY_SCOPE_AGENT);
}
__device__ __forceinline__ void st_rlx(uint* p, uint v) {
    __hip_atomic_store(p, v, __ATOMIC_RELAXED, __HIP_MEMORY_SCOPE_AGENT);
}
__device__ __forceinline__ uint add_rlx(uint* p, uint v) {
    return __hip_atomic_fetch_add(p, v, __ATOMIC_RELAXED, __HIP_MEMORY_SCOPE_AGENT);
}
// 32B state read straight from MALL (bypass L1+L2): two dwordx4 with sc0 sc1.
__device__ __forceinline__ void ld_state(const uint* p, uintx4& a, uintx4& b) {
    asm volatile("global_load_dwordx4 %0, %1, off sc0 sc1"
                 : "=v"(a) : "v"(p) : "memory");
    asm volatile("global_load_dwordx4 %0, %1, off offset:16 sc0 sc1"
                 : "=v"(b) : "v"(p) : "memory");
}
// packed uint = hi16 | lo16<<16 ; split 8 packed words into hi/lo bf16x8 frags
__device__ __forceinline__ bf16x8 hi_frag(uintx4 a, uintx4 b) {
    uintx4 r;
    r[0] = __builtin_amdgcn_perm(a[1], a[0], 0x05040100u);
    r[1] = __builtin_amdgcn_perm(a[3], a[2], 0x05040100u);
    r[2] = __builtin_amdgcn_perm(b[1], b[0], 0x05040100u);
    r[3] = __builtin_amdgcn_perm(b[3], b[2], 0x05040100u);
    return *(bf16x8*)&r;
}
__device__ __forceinline__ bf16x8 lo_frag(uintx4 a, uintx4 b) {
    uintx4 r;
    r[0] = __builtin_amdgcn_perm(a[1], a[0], 0x07060302u);
    r[1] = __builtin_amdgcn_perm(a[3], a[2], 0x07060302u);
    r[2] = __builtin_amdgcn_perm(b[1], b[0], 0x07060302u);
    r[3] = __builtin_amdgcn_perm(b[3], b[2], 0x07060302u);
    return *(bf16x8*)&r;
}
__device__ __forceinline__ uint pack_hl(float v) {
    ushort hi = bf16_rne(v);
    ushort lo = bf16_rne(v - bf16_to_f(hi));
    return (uint)hi | ((uint)lo << 16);
}

// ---------------- prep: weights -> fused bf16 layout ----------------
__global__ __launch_bounds__(256) void prep_w(
    const float* __restrict__ Wiz, const float* __restrict__ Wir, const float* __restrict__ Wih,
    const float* __restrict__ Whz, const float* __restrict__ Whr, const float* __restrict__ Whh,
    ushort* __restrict__ wcomb)
{
    int tid = blockIdx.x * 256 + threadIdx.x;
    int oct = tid % (KTOT / 8);
    int row = tid / (KTOT / 8);                      // gate*1024 + n
    int gate = row >> 10, n = row & 1023;
    int k0 = oct * 8;
    const float* src; int off;
    if (k0 < NINP) { src = gate == 0 ? Wiz : (gate == 1 ? Wir : Wih); off = n * NINP + k0; }
    else           { src = gate == 0 ? Whz : (gate == 1 ? Whr : Whh); off = n * NHID + (k0 - NINP); }
    ushort* dst = wcomb + (size_t)row * KTOT + k0;
    #pragma unroll
    for (int j = 0; j < 8; ++j) dst[j] = bf16_rne(src[off + j]);
}

// ---------------- prep: packed h0, bias sums, barrier zero ----------------
__global__ __launch_bounds__(256) void prep_misc(
    const float* __restrict__ h0,
    const float* __restrict__ biz, const float* __restrict__ bir, const float* __restrict__ bih,
    const float* __restrict__ bhz, const float* __restrict__ bhr, const float* __restrict__ bhh,
    uint* __restrict__ hp, float* __restrict__ bsum, uint* __restrict__ bar)
{
    if (blockIdx.x < 256) {
        int i = blockIdx.x * 256 + threadIdx.x;
        hp[i] = pack_hl(h0[i]);
    } else {
        for (int n = threadIdx.x; n < NHID; n += 256) {
            bsum[n]            = biz[n] + bhz[n];
            bsum[NHID + n]     = bir[n] + bhr[n];
            bsum[2 * NHID + n] = bih[n] + bhh[n];
        }
        for (int i = threadIdx.x; i < 4096; i += 256) bar[i] = 0u;
    }
}

// ---------------- gang barrier: 64 blocks, monotonic counters, no resets ----
// Producer wave calls arrive after its vmcnt(0) store-drain (lane 0 acts).
// Generation g arrivals: group counter old value g*8..g*8+7; last-of-group adds
// sup; last sup (old == g*8+7) publishes wake = g+1 on 8 lines immediately —
// no reset stores, no drain round-trip on the publish path.
__device__ __forceinline__ void gang_arrive(uint* gbar, int oct, uint g) {
    if ((threadIdx.x & 63) == 0) {
        uint a = add_rlx(&gbar[oct * 32], 1u);
        if (a == g * 8u + 7u) {
            uint s = add_rlx(&gbar[G_SUP], 1u);
            if (s == g * 8u + 7u) {
                #pragma unroll
                for (int w = 0; w < 8; ++w) st_rlx(&gbar[G_WAKE + w * 32], g + 1u);
            }
        }
    }
}
// Every wave polls independently (lane 0), then proceeds — no block-wide sync.
__device__ __forceinline__ void gang_wait(uint* gbar, int oct, uint g) {
    if ((threadIdx.x & 63) == 0) {
        while (ld_rlx(&gbar[G_WAKE + oct * 32]) < g + 1u)
            __builtin_amdgcn_s_sleep(1);
    }
    asm volatile("" ::: "memory");
}

// ---------------- persistent GRU: 256 blocks x 512 threads, 4 gangs ---------
// Gang = mt (batch-row slice); its 64 blocks (all nt) are the only producers/
// consumers of its hp/rhp rows -> private 64-block barrier per gang.
// Waves 0,1 are "state waves" (reduce + elementwise + stores); waves 2-7 only
// load/MFMA/LDS-write. Producer wave arrives right after its own store drain;
// all waves poll the wake line and immediately issue next-phase loads.
__global__ __launch_bounds__(512, 1) void gru_persist(
    const float* __restrict__ x, const float* __restrict__ h0,
    const void* __restrict__ lengths_raw,
    const ushort* __restrict__ wcomb, const float* __restrict__ bsum,
    uint* __restrict__ hp, uint* __restrict__ rhp,
    uint* __restrict__ bar, float* __restrict__ out)
{
    const int bid = blockIdx.x;
    const int nt = bid >> 2, mt = bid & 3;
    const int nbase = nt * 16, mbase = mt * 16;
    const int oct = nt >> 3;                         // 8 groups of 8 within gang
    uint* gbar = bar + (mt << 10);
    const int tid = threadIdx.x;
    const int wv = tid >> 6, lane = tid & 63;
    const int col = lane & 15, quad = lane >> 4;
    const int q8 = quad * 8;

    __shared__ f32x4 lds_acc1[8][2][64];             // 16 KB (z,r partials)
    __shared__ f32x4 lds_acc2[8][64];                // 8 KB  (c partials)
    __shared__ uint  lds_pad[15360];                 // 60 KB -> 1 block/CU

    // ---- weight fragments -> VGPRs (once): 6 K-steps x 3 gates ----
    bf16x8 wfz[6], wfr[6], wfc[6];
    #pragma unroll
    for (int s = 0; s < 6; ++s) {
        const int j = wv + 8 * s;                    // K-step 0..47
        const size_t ko = (size_t)j * 32 + q8;
        wfz[s] = ld8(wcomb + (size_t)(0 * NHID + nbase + col) * KTOT + ko);
        wfr[s] = ld8(wcomb + (size_t)(1 * NHID + nbase + col) * KTOT + ko);
        wfc[s] = ld8(wcomb + (size_t)(2 * NHID + nbase + col) * KTOT + ko);
    }

    const int* l32 = (const int*)lengths_raw;
    const bool is64 = (l32[1] == 0);
    int len[4];
    float h_reg[4];                                  // h(t-1) rows quad*4+i, col
    #pragma unroll
    for (int i = 0; i < 4; ++i) {
        const int b = mbase + quad * 4 + i;
        len[i]   = is64 ? (int)((const long long*)lengths_raw)[b] : l32[b];
        h_reg[i] = h0[(size_t)b * NHID + nbase + col];
    }

    const float bias_z = bsum[nbase + col];
    const float bias_r = bsum[NHID + nbase + col];
    const float bias_c = bsum[2 * NHID + nbase + col];

    const size_t arow = (size_t)(mbase + col);       // A-operand row (batch)

    // loop-invariant pointers
    const uint* hpp[4]; const uint* rpp[4]; size_t gi4[4];
    #pragma unroll
    for (int s = 0; s < 4; ++s) {
        const int kh = (wv + 8 * (s + 2)) * 32 - NINP;
        hpp[s] = hp  + arow * NHID + kh + q8;
        rpp[s] = rhp + arow * NHID + kh + q8;
    }
    #pragma unroll
    for (int i = 0; i < 4; ++i)
        gi4[i] = (size_t)(mbase + quad * 4 + i) * NHID + nbase + col;

    f32x4 zsig = zero4();
    bf16x8 xf[2];
    uint bgen = 0;

    // prologue: t=0 x-region
    f32x4 az = zero4(), ar = zero4();
    #pragma unroll
    for (int s = 0; s < 2; ++s) {
        const int k = (wv + 8 * s) * 32;
        xf[s] = cvt8(x + arow * NINP + k + q8);
        az = MFMA(xf[s], wfz[s], az);
        ar = MFMA(xf[s], wfr[s], ar);
    }

    for (int t = 0; t < T_STEPS; ++t) {
        // ================= phase 1: z, r (h region) =================
        {
            uintx4 qa[4], qb[4];
            #pragma unroll
            for (int s = 0; s < 4; ++s) ld_state(hpp[s], qa[s], qb[s]);
            asm volatile("s_waitcnt vmcnt(0)" ::: "memory");
            __builtin_amdgcn_sched_barrier(0);
            #pragma unroll
            for (int s = 0; s < 4; ++s) {
                const bf16x8 hi = hi_frag(qa[s], qb[s]);
                const bf16x8 lo = lo_frag(qa[s], qb[s]);
                az = MFMA(hi, wfz[s + 2], az);
                ar = MFMA(hi, wfr[s + 2], ar);
                az = MFMA(lo, wfz[s + 2], az);
                ar = MFMA(lo, wfr[s + 2], ar);
            }
        }
        lds_acc1[wv][0][lane] = az;
        lds_acc1[wv][1][lane] = ar;
        __syncthreads();                             // phase-1 hand-off
        if (wv == 0) {
            // critical path: r -> rh -> store -> drain -> arrive
            f32x4 rp = {bias_r, bias_r, bias_r, bias_r};
            #pragma unroll
            for (int w = 0; w < 8; ++w) {
                const f32x4 a = lds_acc1[w][1][lane];
                #pragma unroll
                for (int i = 0; i < 4; ++i) rp[i] += a[i];
            }
            #pragma unroll
            for (int i = 0; i < 4; ++i)
                st_rlx(&rhp[gi4[i]], pack_hl(sigmoidf_(rp[i]) * h_reg[i]));
            asm volatile("s_waitcnt vmcnt(0)" ::: "memory");
            gang_arrive(gbar, oct, bgen);
        }
        if (wv < 2) {
            // z reduce off the critical path (after arrive)
            f32x4 zp = {bias_z, bias_z, bias_z, bias_z};
            #pragma unroll
            for (int w = 0; w < 8; ++w) {
                const f32x4 a = lds_acc1[w][0][lane];
                #pragma unroll
                for (int i = 0; i < 4; ++i) zp[i] += a[i];
            }
            #pragma unroll
            for (int i = 0; i < 4; ++i) zsig[i] = sigmoidf_(zp[i]);
        }
        f32x4 ac = zero4();                          // candidate x-part in window
        ac = MFMA(xf[0], wfc[0], ac);
        ac = MFMA(xf[1], wfc[1], ac);
        gang_wait(gbar, oct, bgen); bgen++;          // A: rh durable device-wide

        // ================= phase 2: c, h update =================
        {
            uintx4 qa[4], qb[4];
            #pragma unroll
            for (int s = 0; s < 4; ++s) ld_state(rpp[s], qa[s], qb[s]);
            asm volatile("s_waitcnt vmcnt(0)" ::: "memory");
            __builtin_amdgcn_sched_barrier(0);
            #pragma unroll
            for (int s = 0; s < 4; ++s) {
                const bf16x8 hi = hi_frag(qa[s], qb[s]);
                const bf16x8 lo = lo_frag(qa[s], qb[s]);
                ac = MFMA(hi, wfc[s + 2], ac);
                ac = MFMA(lo, wfc[s + 2], ac);
            }
        }
        lds_acc2[wv][lane] = ac;
        __syncthreads();                             // phase-2 hand-off
        if (wv < 2) {
            f32x4 cp = {bias_c, bias_c, bias_c, bias_c};
            #pragma unroll
            for (int w = 0; w < 8; ++w) {
                const f32x4 a = lds_acc2[w][lane];
                #pragma unroll
                for (int i = 0; i < 4; ++i) cp[i] += a[i];
            }
            float hn4[4];
            #pragma unroll
            for (int i = 0; i < 4; ++i) {
                const float c = tanhf_(cp[i]);
                const float h = h_reg[i];
                hn4[i] = (t < len[i]) ? fmaf(zsig[i], c - h, h) : h;
                h_reg[i] = hn4[i];
            }
            if (wv == 1) {
                // critical path: h store -> drain -> arrive
                #pragma unroll
                for (int i = 0; i < 4; ++i) st_rlx(&hp[gi4[i]], pack_hl(hn4[i]));
                asm volatile("s_waitcnt vmcnt(0)" ::: "memory");
                gang_arrive(gbar, oct, bgen);
            } else {
                float* out_t = out + (size_t)t * BN;
                #pragma unroll
                for (int i = 0; i < 4; ++i) {
                    __builtin_nontemporal_store(hn4[i], &out_t[gi4[i]]);
                    if (t == T_STEPS - 1)
                        __builtin_nontemporal_store(hn4[i], &out[(size_t)T_STEPS * BN + gi4[i]]);
                }
            }
        }
        az = zero4(); ar = zero4();                  // next-step x in window
        if (t + 1 < T_STEPS) {
            const float* x_t = x + (size_t)(t + 1) * B_SZ * NINP;
            #pragma unroll
            for (int s = 0; s < 2; ++s) {
                const int k = (wv + 8 * s) * 32;
                xf[s] = cvt8(x_t + arow * NINP + k + q8);
                az = MFMA(xf[s], wfz[s], az);
                ar = MFMA(xf[s], wfr[s], ar);
            }
        }
        gang_wait(gbar, oct, bgen); bgen++;          // B: h durable device-wide
    }

    // keep lds_pad allocated (unprovable guard; never executes)
    if (blockIdx.x == 0xFFFFFFFFu) {
        lds_pad[threadIdx.x] = bgen;
        out[0] = (float)lds_pad[threadIdx.x];
    }
}

// ws_size probe: no-op; gridDim.x = ws_size_in_MB + 1 (read from rocprof dims).
__global__ void gru_ws_probe_mb(float* p) {
    if (blockIdx.x == 0xFFFFFFFFu) p[0] = 0.f;
}

extern "C" void kernel_launch(void* const* d_in, const int* in_sizes, int n_in,
                              void* d_out, int out_size, void* d_ws, size_t ws_size,
                              hipStream_t stream) {
    const float* x   = (const float*)d_in[0];
    const float* h0  = (const float*)d_in[1];
    const float* Wiz = (const float*)d_in[2];  const float* biz = (const float*)d_in[3];
    const float* Wir = (const float*)d_in[4];  const float* bir = (const float*)d_in[5];
    const float* Wih = (const float*)d_in[6];  const float* bih = (const float*)d_in[7];
    const float* Whz = (const float*)d_in[8];  const float* bhz = (const float*)d_in[9];
    const float* Whr = (const float*)d_in[10]; const float* bhr = (const float*)d_in[11];
    const float* Whh = (const float*)d_in[12]; const float* bhh = (const float*)d_in[13];
    const void*  lengths = d_in[14];
    float* out = (float*)d_out;
    char*  ws  = (char*)d_ws;

    size_t mb = ws_size >> 20; if (mb > 2048) mb = 2048;
    gru_ws_probe_mb<<<dim3((uint)mb + 1), 64, 0, stream>>>((float*)d_ws);
    if (ws_size < (size_t)WS_NEED) return;

    ushort* wcomb = (ushort*)ws;
    float*  bsum  = (float*)(ws + WS_BSUM);
    uint*   hp    = (uint*)(ws + WS_HP);
    uint*   rhp   = (uint*)(ws + WS_RHP);
    uint*   bar   = (uint*)(ws + WS_BAR);

    prep_w<<<2304, 256, 0, stream>>>(Wiz, Wir, Wih, Whz, Whr, Whh, wcomb);
    prep_misc<<<257, 256, 0, stream>>>(h0, biz, bir, bih, bhz, bhr, bhh, hp, bsum, bar);
    gru_persist<<<256, 512, 0, stream>>>(x, h0, lengths, wcomb, bsum,
                                         hp, rhp, bar, out);
}

// Round 4
// 4141.106 us; speedup vs baseline: 10.8433x; 1.1498x over previous
//
#include <hip/hip_runtime.h>

typedef unsigned int   uint;
typedef unsigned short ushort;

#define NINP    512
#define NHID    1024
#define T_STEPS 512
#define B_SZ    64
#define KTOT    1536                 // NINP + NHID fused K
#define BN      (B_SZ * NHID)        // 65536

typedef __attribute__((ext_vector_type(8))) short bf16x8;
typedef __attribute__((ext_vector_type(4))) float f32x4;
typedef __attribute__((ext_vector_type(4))) uint  uintx4;

// ---------------- ws layout (bytes) ----------------
#define WCOMB_BYTES (3 * NHID * KTOT * 2)            // 9,437,184
#define WS_BSUM     (WCOMB_BYTES)                    // f32 [3][1024]
#define WS_HP       (WS_BSUM + 3 * NHID * 4)         // uint [64][1024] packed h  (hi|lo<<16)
#define WS_RHP      (WS_HP + BN * 4)                 // uint [64][1024] packed r*h
#define WS_BAR      (WS_RHP + BN * 4)                // flags: 2 arrays x 4 gangs x 64 x 128B
#define WS_NEED     (WS_BAR + 65536)

// flag arrays (uint indices from bar): flag_r[mt][nt] at (mt*64+nt)*32,
// flag_h at FH_OFF + same. One flag per 128B line. Monotonic, never reset.
#define FH_OFF  8192

__device__ __forceinline__ float sigmoidf_(float x) { return 1.0f / (1.0f + __expf(-x)); }
__device__ __forceinline__ float tanhf_(float x)    { return 1.0f - 2.0f / (__expf(2.0f * x) + 1.0f); }

__device__ __forceinline__ ushort bf16_rne(float f) {
    uint u = __float_as_uint(f);
    return (ushort)((u + 0x7FFFu + ((u >> 16) & 1u)) >> 16);
}
__device__ __forceinline__ float bf16_to_f(ushort s) { return __uint_as_float(((uint)s) << 16); }
__device__ __forceinline__ bf16x8 ld8(const ushort* p) { return *(const bf16x8*)p; }
__device__ __forceinline__ bf16x8 cvt8(const float* p) {
    float4 a = *(const float4*)p;
    float4 b = *(const float4*)(p + 4);
    bf16x8 r;
    r[0] = (short)bf16_rne(a.x); r[1] = (short)bf16_rne(a.y);
    r[2] = (short)bf16_rne(a.z); r[3] = (short)bf16_rne(a.w);
    r[4] = (short)bf16_rne(b.x); r[5] = (short)bf16_rne(b.y);
    r[6] = (short)bf16_rne(b.z); r[7] = (short)bf16_rne(b.w);
    return r;
}
__device__ __forceinline__ f32x4 zero4() { f32x4 z = {0.f, 0.f, 0.f, 0.f}; return z; }
#define MFMA(a, b, c) __builtin_amdgcn_mfma_f32_16x16x32_bf16((a), (b), (c), 0, 0, 0)

// ---------------- MALL-coherent primitives (no cache-maintenance fences) ----
__device__ __forceinline__ uint ld_rlx(uint* p) {
    return __hip_atomic_load(p, __ATOMIC_RELAXED, __HIP_MEMORY_SCOPE_AGENT);
}
__device__ __forceinline__ void st_rlx(uint* p, uint v) {
    __hip_atomic_store(p, v, __ATOMIC_RELAXED, __HIP_MEMORY_SCOPE_AGENT);
}
// 32B state read straight from MALL (bypass L1+L2): two dwordx4 with sc0 sc1.
__device__ __forceinline__ void ld_state(const uint* p, uintx4& a, uintx4& b) {
    asm volatile("global_load_dwordx4 %0, %1, off sc0 sc1"
                 : "=v"(a) : "v"(p) : "memory");
    asm volatile("global_load_dwordx4 %0, %1, off offset:16 sc0 sc1"
                 : "=v"(b) : "v"(p) : "memory");
}
// Poll a per-lane flag pointer (8 distinct producers replicated across 64
// lanes) until ALL flags >= target. One dword MALL load per iteration.
__device__ __forceinline__ void poll_ge(const uint* p, uint target) {
    for (;;) {
        uint v;
        asm volatile("global_load_dword %0, %1, off sc0 sc1\n\t"
                     "s_waitcnt vmcnt(0)"
                     : "=v"(v) : "v"(p) : "memory");
        if (__all(v >= target)) break;
        __builtin_amdgcn_s_sleep(1);
    }
}
// packed uint = hi16 | lo16<<16 ; split 8 packed words into hi/lo bf16x8 frags
__device__ __forceinline__ bf16x8 hi_frag(uintx4 a, uintx4 b) {
    uintx4 r;
    r[0] = __builtin_amdgcn_perm(a[1], a[0], 0x05040100u);
    r[1] = __builtin_amdgcn_perm(a[3], a[2], 0x05040100u);
    r[2] = __builtin_amdgcn_perm(b[1], b[0], 0x05040100u);
    r[3] = __builtin_amdgcn_perm(b[3], b[2], 0x05040100u);
    return *(bf16x8*)&r;
}
__device__ __forceinline__ bf16x8 lo_frag(uintx4 a, uintx4 b) {
    uintx4 r;
    r[0] = __builtin_amdgcn_perm(a[1], a[0], 0x07060302u);
    r[1] = __builtin_amdgcn_perm(a[3], a[2], 0x07060302u);
    r[2] = __builtin_amdgcn_perm(b[1], b[0], 0x07060302u);
    r[3] = __builtin_amdgcn_perm(b[3], b[2], 0x07060302u);
    return *(bf16x8*)&r;
}
__device__ __forceinline__ uint pack_hl(float v) {
    ushort hi = bf16_rne(v);
    ushort lo = bf16_rne(v - bf16_to_f(hi));
    return (uint)hi | ((uint)lo << 16);
}

// ---------------- prep: weights -> fused bf16 layout ----------------
__global__ __launch_bounds__(256) void prep_w(
    const float* __restrict__ Wiz, const float* __restrict__ Wir, const float* __restrict__ Wih,
    const float* __restrict__ Whz, const float* __restrict__ Whr, const float* __restrict__ Whh,
    ushort* __restrict__ wcomb)
{
    int tid = blockIdx.x * 256 + threadIdx.x;
    int oct = tid % (KTOT / 8);
    int row = tid / (KTOT / 8);                      // gate*1024 + n
    int gate = row >> 10, n = row & 1023;
    int k0 = oct * 8;
    const float* src; int off;
    if (k0 < NINP) { src = gate == 0 ? Wiz : (gate == 1 ? Wir : Wih); off = n * NINP + k0; }
    else           { src = gate == 0 ? Whz : (gate == 1 ? Whr : Whh); off = n * NHID + (k0 - NINP); }
    ushort* dst = wcomb + (size_t)row * KTOT + k0;
    #pragma unroll
    for (int j = 0; j < 8; ++j) dst[j] = bf16_rne(src[off + j]);
}

// ---------------- prep: packed h0, bias sums, flag zero ----------------
__global__ __launch_bounds__(256) void prep_misc(
    const float* __restrict__ h0,
    const float* __restrict__ biz, const float* __restrict__ bir, const float* __restrict__ bih,
    const float* __restrict__ bhz, const float* __restrict__ bhr, const float* __restrict__ bhh,
    uint* __restrict__ hp, float* __restrict__ bsum, uint* __restrict__ bar)
{
    if (blockIdx.x < 256) {
        int i = blockIdx.x * 256 + threadIdx.x;
        hp[i] = pack_hl(h0[i]);
    } else {
        for (int n = threadIdx.x; n < NHID; n += 256) {
            bsum[n]            = biz[n] + bhz[n];
            bsum[NHID + n]     = bir[n] + bhr[n];
            bsum[2 * NHID + n] = bih[n] + bhh[n];
        }
        for (int i = threadIdx.x; i < 16384; i += 256) bar[i] = 0u;
    }
}

// ---------------- persistent GRU: 256 blocks x 512 threads, barrier-free ----
// Block = (nt, mt): n-cols [nt*16,+16), batch rows [mt*16,+16). 8 waves split
// fused K=1536: wave wv does K-steps j = wv + 8s (s=0..5; s<2 x, s>=2 h).
// Synchronization is pure dataflow: producer block (nt,mt) stores its state
// slice, drains vmcnt, then publishes flag = t+1. Consumer wave polls only
// the 8 producer flags covering its K-slots (k-chunk [wv*32+256s, +32) ->
// producers 2wv+16s, 2wv+16s+1), then MALL-loads the data. The happens-before
// chain (producer's phase syncthreads precedes its flag; consumer block's
// next store follows all its waves' polls) makes overwrites impossible with
// no grid barrier at all. lds_acc1 is parity-double-buffered (z-partials are
// read after the rh flag is published); lds_acc2 is provably safe single.
__global__ __launch_bounds__(512, 1) void gru_persist(
    const float* __restrict__ x, const float* __restrict__ h0,
    const void* __restrict__ lengths_raw,
    const ushort* __restrict__ wcomb, const float* __restrict__ bsum,
    uint* __restrict__ hp, uint* __restrict__ rhp,
    uint* __restrict__ bar, float* __restrict__ out)
{
    const int bid = blockIdx.x;
    const int nt = bid >> 2, mt = bid & 3;
    const int nbase = nt * 16, mbase = mt * 16;
    const int tid = threadIdx.x;
    const int wv = tid >> 6, lane = tid & 63;
    const int col = lane & 15, quad = lane >> 4;
    const int q8 = quad * 8;

    __shared__ f32x4 lds_acc1[2][8][2][64];          // 32 KB (z,r partials, parity)
    __shared__ f32x4 lds_acc2[8][64];                // 8 KB  (c partials)
    __shared__ uint  lds_pad[11264];                 // 44 KB -> 84 KB total -> 1 block/CU
    lds_pad[tid & 1023] = tid;                       // keep pad live

    // per-lane flag pointers: producer nt' = 2wv + 16*(pslot>>1) + (pslot&1)
    const int pslot = lane & 7;
    const int prod  = 2 * wv + 16 * (pslot >> 1) + (pslot & 1);
    uint* fr_ptr = bar + ((size_t)(mt * 64 + prod)) * 32;          // rh flags
    uint* fh_ptr = bar + FH_OFF + ((size_t)(mt * 64 + prod)) * 32; // h flags
    uint* my_fr  = bar + ((size_t)(mt * 64 + nt)) * 32;
    uint* my_fh  = bar + FH_OFF + ((size_t)(mt * 64 + nt)) * 32;

    // ---- weight fragments -> VGPRs (once): 6 K-steps x 3 gates ----
    bf16x8 wfz[6], wfr[6], wfc[6];
    #pragma unroll
    for (int s = 0; s < 6; ++s) {
        const int j = wv + 8 * s;                    // K-step 0..47
        const size_t ko = (size_t)j * 32 + q8;
        wfz[s] = ld8(wcomb + (size_t)(0 * NHID + nbase + col) * KTOT + ko);
        wfr[s] = ld8(wcomb + (size_t)(1 * NHID + nbase + col) * KTOT + ko);
        wfc[s] = ld8(wcomb + (size_t)(2 * NHID + nbase + col) * KTOT + ko);
    }

    const int* l32 = (const int*)lengths_raw;
    const bool is64 = (l32[1] == 0);
    int len[4];
    float h_reg[4];                                  // h(t-1) rows quad*4+i, col
    #pragma unroll
    for (int i = 0; i < 4; ++i) {
        const int b = mbase + quad * 4 + i;
        len[i]   = is64 ? (int)((const long long*)lengths_raw)[b] : l32[b];
        h_reg[i] = h0[(size_t)b * NHID + nbase + col];
    }

    const float bias_z = bsum[nbase + col];
    const float bias_r = bsum[NHID + nbase + col];
    const float bias_c = bsum[2 * NHID + nbase + col];

    const size_t arow = (size_t)(mbase + col);       // A-operand row (batch)

    // loop-invariant pointers
    const uint* hpp[4]; const uint* rpp[4]; size_t gi4[4];
    #pragma unroll
    for (int s = 0; s < 4; ++s) {
        const int kh = (wv + 8 * (s + 2)) * 32 - NINP;
        hpp[s] = hp  + arow * NHID + kh + q8;
        rpp[s] = rhp + arow * NHID + kh + q8;
    }
    #pragma unroll
    for (int i = 0; i < 4; ++i)
        gi4[i] = (size_t)(mbase + quad * 4 + i) * NHID + nbase + col;

    f32x4 zsig = zero4();
    bf16x8 xf[2];

    // prologue: t=0 x-region
    f32x4 az = zero4(), ar = zero4();
    #pragma unroll
    for (int s = 0; s < 2; ++s) {
        const int k = (wv + 8 * s) * 32;
        xf[s] = cvt8(x + arow * NINP + k + q8);
        az = MFMA(xf[s], wfz[s], az);
        ar = MFMA(xf[s], wfr[s], ar);
    }

    for (int t = 0; t < T_STEPS; ++t) {
        const int par = t & 1;
        // ================= phase 1: z, r (h region) =================
        if (t) poll_ge(fh_ptr, (uint)t);             // hp(t-1) ready at my slots
        {
            uintx4 qa[4], qb[4];
            #pragma unroll
            for (int s = 0; s < 4; ++s) ld_state(hpp[s], qa[s], qb[s]);
            asm volatile("s_waitcnt vmcnt(0)" ::: "memory");
            __builtin_amdgcn_sched_barrier(0);
            #pragma unroll
            for (int s = 0; s < 4; ++s) {
                const bf16x8 hi = hi_frag(qa[s], qb[s]);
                const bf16x8 lo = lo_frag(qa[s], qb[s]);
                az = MFMA(hi, wfz[s + 2], az);
                ar = MFMA(hi, wfr[s + 2], ar);
                az = MFMA(lo, wfz[s + 2], az);
                ar = MFMA(lo, wfr[s + 2], ar);
            }
        }
        lds_acc1[par][wv][0][lane] = az;
        lds_acc1[par][wv][1][lane] = ar;
        __syncthreads();                             // phase-1 hand-off
        if (wv == 0) {
            // critical path: r-reduce -> rh -> store -> drain -> flag
            f32x4 rp = {bias_r, bias_r, bias_r, bias_r};
            #pragma unroll
            for (int w = 0; w < 8; ++w) {
                const f32x4 a = lds_acc1[par][w][1][lane];
                #pragma unroll
                for (int i = 0; i < 4; ++i) rp[i] += a[i];
            }
            #pragma unroll
            for (int i = 0; i < 4; ++i)
                st_rlx(&rhp[gi4[i]], pack_hl(sigmoidf_(rp[i]) * h_reg[i]));
            asm volatile("s_waitcnt vmcnt(0)" ::: "memory");
            if (lane == 0) st_rlx(my_fr, (uint)(t + 1));
        }
        if (wv < 2) {
            // z-reduce off the critical path (after flag publish)
            f32x4 zp = {bias_z, bias_z, bias_z, bias_z};
            #pragma unroll
            for (int w = 0; w < 8; ++w) {
                const f32x4 a = lds_acc1[par][w][0][lane];
                #pragma unroll
                for (int i = 0; i < 4; ++i) zp[i] += a[i];
            }
            #pragma unroll
            for (int i = 0; i < 4; ++i) zsig[i] = sigmoidf_(zp[i]);
        }
        f32x4 ac = zero4();                          // candidate x-part while waiting
        ac = MFMA(xf[0], wfc[0], ac);
        ac = MFMA(xf[1], wfc[1], ac);

        // ================= phase 2: c, h update =================
        poll_ge(fr_ptr, (uint)(t + 1));              // rh(t) ready at my slots
        {
            uintx4 qa[4], qb[4];
            #pragma unroll
            for (int s = 0; s < 4; ++s) ld_state(rpp[s], qa[s], qb[s]);
            asm volatile("s_waitcnt vmcnt(0)" ::: "memory");
            __builtin_amdgcn_sched_barrier(0);
            #pragma unroll
            for (int s = 0; s < 4; ++s) {
                const bf16x8 hi = hi_frag(qa[s], qb[s]);
                const bf16x8 lo = lo_frag(qa[s], qb[s]);
                ac = MFMA(hi, wfc[s + 2], ac);
                ac = MFMA(lo, wfc[s + 2], ac);
            }
        }
        lds_acc2[wv][lane] = ac;
        __syncthreads();                             // phase-2 hand-off
        if (wv < 2) {
            f32x4 cp = {bias_c, bias_c, bias_c, bias_c};
            #pragma unroll
            for (int w = 0; w < 8; ++w) {
                const f32x4 a = lds_acc2[w][lane];
                #pragma unroll
                for (int i = 0; i < 4; ++i) cp[i] += a[i];
            }
            float hn4[4];
            #pragma unroll
            for (int i = 0; i < 4; ++i) {
                const float c = tanhf_(cp[i]);
                const float h = h_reg[i];
                hn4[i] = (t < len[i]) ? fmaf(zsig[i], c - h, h) : h;
                h_reg[i] = hn4[i];
            }
            if (wv == 1) {
                // critical path: h store -> drain -> flag
                #pragma unroll
                for (int i = 0; i < 4; ++i) st_rlx(&hp[gi4[i]], pack_hl(hn4[i]));
                asm volatile("s_waitcnt vmcnt(0)" ::: "memory");
                if (lane == 0) st_rlx(my_fh, (uint)(t + 1));
            } else {
                float* out_t = out + (size_t)t * BN;
                #pragma unroll
                for (int i = 0; i < 4; ++i) {
                    __builtin_nontemporal_store(hn4[i], &out_t[gi4[i]]);
                    if (t == T_STEPS - 1)
                        __builtin_nontemporal_store(hn4[i], &out[(size_t)T_STEPS * BN + gi4[i]]);
                }
            }
        }
        az = zero4(); ar = zero4();                  // next-step x while others produce
        if (t + 1 < T_STEPS) {
            const float* x_t = x + (size_t)(t + 1) * B_SZ * NINP;
            #pragma unroll
            for (int s = 0; s < 2; ++s) {
                const int k = (wv + 8 * s) * 32;
                xf[s] = cvt8(x_t + arow * NINP + k + q8);
                az = MFMA(xf[s], wfz[s], az);
                ar = MFMA(xf[s], wfr[s], ar);
            }
        }
    }

    // unprovable runtime guard keeps lds_pad from being stripped
    if (ld_rlx(&bar[1023]) == 0xDEADBEEFu)
        out[0] = (float)lds_pad[tid & 1023];
}

// ws_size probe: no-op; gridDim.x = ws_size_in_MB + 1 (read from rocprof dims).
__global__ void gru_ws_probe_mb(float* p) {
    if (blockIdx.x == 0xFFFFFFFFu) p[0] = 0.f;
}

extern "C" void kernel_launch(void* const* d_in, const int* in_sizes, int n_in,
                              void* d_out, int out_size, void* d_ws, size_t ws_size,
                              hipStream_t stream) {
    const float* x   = (const float*)d_in[0];
    const float* h0  = (const float*)d_in[1];
    const float* Wiz = (const float*)d_in[2];  const float* biz = (const float*)d_in[3];
    const float* Wir = (const float*)d_in[4];  const float* bir = (const float*)d_in[5];
    const float* Wih = (const float*)d_in[6];  const float* bih = (const float*)d_in[7];
    const float* Whz = (const float*)d_in[8];  const float* bhz = (const float*)d_in[9];
    const float* Whr = (const float*)d_in[10]; const float* bhr = (const float*)d_in[11];
    const float* Whh = (const float*)d_in[12]; const float* bhh = (const float*)d_in[13];
    const void*  lengths = d_in[14];
    float* out = (float*)d_out;
    char*  ws  = (char*)d_ws;

    size_t mb = ws_size >> 20; if (mb > 2048) mb = 2048;
    gru_ws_probe_mb<<<dim3((uint)mb + 1), 64, 0, stream>>>((float*)d_ws);
    if (ws_size < (size_t)WS_NEED) return;

    ushort* wcomb = (ushort*)ws;
    float*  bsum  = (float*)(ws + WS_BSUM);
    uint*   hp    = (uint*)(ws + WS_HP);
    uint*   rhp   = (uint*)(ws + WS_RHP);
    uint*   bar   = (uint*)(ws + WS_BAR);

    prep_w<<<2304, 256, 0, stream>>>(Wiz, Wir, Wih, Whz, Whr, Whh, wcomb);
    prep_misc<<<257, 256, 0, stream>>>(h0, biz, bir, bih, bhz, bhr, bhh, hp, bsum, bar);
    gru_persist<<<256, 512, 0, stream>>>(x, h0, lengths, wcomb, bsum,
                                         hp, rhp, bar, out);
}